// Round 5
// baseline (680.787 us; speedup 1.0000x reference)
//
#include <hip/hip_runtime.h>
#include <math.h>

// =====================================================================
// 3-layer GAT (PyG GATConv) on MI355X.
// fp32 data plane + split-precision bf16 MFMA GEMMs (hi/lo, fp32-equiv).
// CSR-by-dst gather aggregation with merged-head online softmax.
// R5: GEMM single-pass over A (CT=16, no column-tile replication);
//     aggregate inner gather fully unrolled (16 independent loads).
// =====================================================================

#define NEG_SLOPE 0.2f

typedef unsigned short u16;
typedef short bf16x8 __attribute__((ext_vector_type(8)));
typedef float floatx4 __attribute__((ext_vector_type(4)));

__device__ __forceinline__ float b2f(u16 u) {
    return __uint_as_float(((unsigned int)u) << 16);
}
__device__ __forceinline__ u16 f2b(float f) {
    unsigned int u = __float_as_uint(f);
    unsigned int r = (u + 0x7fffu + ((u >> 16) & 1u)) >> 16;   // RNE
    return (u16)r;
}

// ---------------- CSR build ----------------

__global__ __launch_bounds__(256) void edge_count(const int* __restrict__ ei, int E, int n,
                                                  int* __restrict__ deg) {
    int e = blockIdx.x * blockDim.x + threadIdx.x;
    int Etot = E + n;
    if (e >= Etot) return;
    int dst = (e < E) ? ei[E + e] : (e - E);   // self-loop for e >= E
    atomicAdd(&deg[dst], 1);
}

__global__ __launch_bounds__(1024) void scan_kernel(const int* __restrict__ deg,
                                                    int* __restrict__ offs,
                                                    int* __restrict__ cursor, int n) {
    __shared__ int sdata[1024];
    __shared__ int s_running;
    if (threadIdx.x == 0) s_running = 0;
    __syncthreads();
    const int CHUNK = 1024 * 8;
    for (int base = 0; base < n; base += CHUNK) {
        int vals[8];
        int sum = 0;
#pragma unroll
        for (int r = 0; r < 8; ++r) {
            int i = base + threadIdx.x * 8 + r;
            vals[r] = (i < n) ? deg[i] : 0;
            sum += vals[r];
        }
        sdata[threadIdx.x] = sum;
        __syncthreads();
        for (int off = 1; off < 1024; off <<= 1) {
            int v = (threadIdx.x >= off) ? sdata[threadIdx.x - off] : 0;
            __syncthreads();
            sdata[threadIdx.x] += v;
            __syncthreads();
        }
        int excl = sdata[threadIdx.x] - sum + s_running;
#pragma unroll
        for (int r = 0; r < 8; ++r) {
            int i = base + threadIdx.x * 8 + r;
            if (i < n) { offs[i] = excl; cursor[i] = excl; }
            excl += vals[r];
        }
        __syncthreads();
        if (threadIdx.x == 0) s_running += sdata[1023];
        __syncthreads();
    }
    if (threadIdx.x == 0) offs[n] = s_running;
}

__global__ __launch_bounds__(256) void edge_fill(const int* __restrict__ ei, int E, int n,
                                                 int* __restrict__ cursor,
                                                 int* __restrict__ csr) {
    int e = blockIdx.x * blockDim.x + threadIdx.x;
    int Etot = E + n;
    if (e >= Etot) return;
    int src, dst;
    if (e < E) { src = ei[e]; dst = ei[E + e]; }
    else       { src = e - E; dst = e - E; }
    int pos = atomicAdd(&cursor[dst], 1);
    csr[pos] = src;
}

// -------- Weight transpose + hi/lo bf16 split: Wt[n][k] = W[k][n] --------

__global__ __launch_bounds__(256) void transpose_split(const float* __restrict__ W,
                                                       u16* __restrict__ Whi,
                                                       u16* __restrict__ Wlo, int K, int N) {
    int idx = blockIdx.x * blockDim.x + threadIdx.x;
    if (idx >= K * N) return;
    int k = idx / N, c = idx % N;
    float w = W[idx];
    u16 hi = f2b(w);
    u16 lo = f2b(w - b2f(hi));
    Whi[(size_t)c * K + k] = hi;
    Wlo[(size_t)c * K + k] = lo;
}

// ---------------- Layer-1 linear (K=3), fp32 out ----------------

__global__ __launch_bounds__(256) void linear1(const float* __restrict__ x,
                                               const float* __restrict__ W,
                                               float* __restrict__ out, int n) {
    int node = blockIdx.x;
    if (node >= n) return;
    int c = threadIdx.x;
    float x0 = x[node * 3 + 0], x1 = x[node * 3 + 1], x2 = x[node * 3 + 2];
    out[(size_t)node * 256 + c] = fmaf(x0, W[c], fmaf(x1, W[256 + c], x2 * W[512 + c]));
}

// ------- Split-precision MFMA GEMM: out[n x NCOLS] = A[n x 256] * W^T ----
// A fp32 row-major, split to hi/lo bf16 in-register. W pre-split/transposed
// bf16 [NCOLS][256]. D = Ahi*Whi + Alo*Whi + Ahi*Wlo (fp32 acc).
// One block = 64 rows x ALL NCOLS columns -> A fetched exactly once.
// Fragments: A[m=lane&15][k=(lane>>4)*8+j]; D reg r -> row (l>>4)*4+r, col l&15.

template <int NCOLS>
__global__ __launch_bounds__(256) void gemm_mfma_split(const float* __restrict__ A,
                                                       const u16* __restrict__ Whi,
                                                       const u16* __restrict__ Wlo,
                                                       float* __restrict__ outf, int n) {
    constexpr int CT = NCOLS / 16;   // 16 (layer2) or 2 (layer3)
    int w = threadIdx.x >> 6;
    int l = threadIdx.x & 63;
    int m0 = blockIdx.x * 64 + w * 16;
    int lm = l & 15, q = l >> 4;
    floatx4 acc[CT] = {};
    const float* arow = A + (size_t)(m0 + lm) * 256 + q * 8;
#pragma unroll
    for (int kb = 0; kb < 256; kb += 32) {
        float4 a0 = *(const float4*)(arow + kb);
        float4 a1 = *(const float4*)(arow + kb + 4);
        float av[8] = {a0.x, a0.y, a0.z, a0.w, a1.x, a1.y, a1.z, a1.w};
        bf16x8 ahi, alo;
#pragma unroll
        for (int j = 0; j < 8; ++j) {
            u16 hi = f2b(av[j]);
            ahi[j] = (short)hi;
            alo[j] = (short)f2b(av[j] - b2f(hi));
        }
#pragma unroll
        for (int ct = 0; ct < CT; ++ct) {
            size_t boff = (size_t)(ct * 16 + lm) * 256 + kb + q * 8;
            bf16x8 bhi = *(const bf16x8*)(Whi + boff);
            bf16x8 blo = *(const bf16x8*)(Wlo + boff);
            acc[ct] = __builtin_amdgcn_mfma_f32_16x16x32_bf16(ahi, bhi, acc[ct], 0, 0, 0);
            acc[ct] = __builtin_amdgcn_mfma_f32_16x16x32_bf16(alo, bhi, acc[ct], 0, 0, 0);
            acc[ct] = __builtin_amdgcn_mfma_f32_16x16x32_bf16(ahi, blo, acc[ct], 0, 0, 0);
        }
    }
#pragma unroll
    for (int ct = 0; ct < CT; ++ct) {
#pragma unroll
        for (int r = 0; r < 4; ++r) {
            int row = m0 + q * 4 + r;
            if (row < n)
                outf[(size_t)row * NCOLS + ct * 16 + lm] = acc[ct][r];
        }
    }
}

// ---------------- Attention scores: s_src/s_dst = sum_c h*a ----------------

template <int HEADS, int C>
__global__ __launch_bounds__(256) void compute_scores(const float* __restrict__ h,
                                                      const float* __restrict__ asrc,
                                                      const float* __restrict__ adst,
                                                      float* __restrict__ ssrc,
                                                      float* __restrict__ sdst, int n) {
    int w = blockIdx.x * (blockDim.x >> 6) + (threadIdx.x >> 6);
    int lane = threadIdx.x & 63;
    if (w >= n * HEADS) return;
    int node = w / HEADS;
    int head = w % HEADS;
    float va = 0.f, vb = 0.f;
    if (lane < C) {
        float v = h[(size_t)node * (HEADS * C) + head * C + lane];
        va = v * asrc[head * C + lane];
        vb = v * adst[head * C + lane];
    }
#pragma unroll
    for (int o = 32; o > 0; o >>= 1) {
        va += __shfl_xor(va, o);
        vb += __shfl_xor(vb, o);
    }
    if (lane == 0) { ssrc[w] = va; sdst[w] = vb; }
}

// ---------------- Merged 4-head aggregation (layers 1 & 2) ----------------
// One wave per dst node. Lane l: float4 acc covering channels l*4..l*4+3
// (head hA = l>>4); softmax state for head hB = l&3, edge slot eL = l>>2.
// Inner gather fully unrolled: invalid slots read row 0 (L1-resident) with
// weight 0 -> 16 independent dwordx4 gathers in flight per chunk.

__global__ __launch_bounds__(256) void gat_aggregate_m4(const float* __restrict__ h,
                                                        const float* __restrict__ ssrc,
                                                        const float* __restrict__ sdst,
                                                        const int* __restrict__ offs,
                                                        const int* __restrict__ csr,
                                                        const float* __restrict__ bias,
                                                        float* __restrict__ out, int n) {
    int node = blockIdx.x * 4 + (threadIdx.x >> 6);
    int lane = threadIdx.x & 63;
    if (node >= n) return;
    const int hB = lane & 3;
    const int eL = lane >> 2;
    const int hA = lane >> 4;
    int beg = offs[node], end = offs[node + 1];
    float sd = sdst[node * 4 + hB];
    float m = -INFINITY, l = 0.f;
    float4 acc = make_float4(0.f, 0.f, 0.f, 0.f);

    for (int base = beg; base < end; base += 16) {
        int j = base + eL;
        bool valid = (j < end);
        int sj = valid ? csr[j] : 0;
        float logit = -INFINITY;
        if (valid) {
            float xv = ssrc[sj * 4 + hB] + sd;
            logit = (xv > 0.f) ? xv : NEG_SLOPE * xv;
        }
        float cm = logit;
        cm = fmaxf(cm, __shfl_xor(cm, 4));
        cm = fmaxf(cm, __shfl_xor(cm, 8));
        cm = fmaxf(cm, __shfl_xor(cm, 16));
        cm = fmaxf(cm, __shfl_xor(cm, 32));
        float nm = fmaxf(m, cm);
        float scale = __expf(m - nm);       // m=-inf -> 0
        float ex = valid ? __expf(logit - nm) : 0.f;   // 0 for invalid slots
        float es = ex;
        es += __shfl_xor(es, 4);
        es += __shfl_xor(es, 8);
        es += __shfl_xor(es, 16);
        es += __shfl_xor(es, 32);
        l = l * scale + es;
        m = nm;
        float sA = __shfl(scale, hA);
        acc.x *= sA; acc.y *= sA; acc.z *= sA; acc.w *= sA;

#pragma unroll
        for (int t = 0; t < 16; ++t) {
            float a = __shfl(ex, t * 4 + hA);   // 0 for invalid edges
            int s = __shfl(sj, t * 4);          // 0 for invalid (safe addr, L1 hit)
            const float4 hv = *(const float4*)&h[(size_t)s * 256 + lane * 4];
            acc.x = fmaf(a, hv.x, acc.x);
            acc.y = fmaf(a, hv.y, acc.y);
            acc.z = fmaf(a, hv.z, acc.z);
            acc.w = fmaf(a, hv.w, acc.w);
        }
    }
    float lf = __shfl(l, hA);
    float inv = 1.f / lf;
    const float4 bv = *(const float4*)&bias[lane * 4];
    float4 o;
    o.x = fmaxf(fmaf(acc.x, inv, bv.x), 0.f);   // relu (layers 1 & 2)
    o.y = fmaxf(fmaf(acc.y, inv, bv.y), 0.f);
    o.z = fmaxf(fmaf(acc.z, inv, bv.z), 0.f);
    o.w = fmaxf(fmaf(acc.w, inv, bv.w), 0.f);
    *(float4*)&out[(size_t)node * 256 + lane * 4] = o;
}

// ---------------- Single-head aggregation (layer 3, C=32, no relu) --------

__global__ __launch_bounds__(256) void gat_aggregate_h1(const float* __restrict__ h,
                                                        const float* __restrict__ ssrc,
                                                        const float* __restrict__ sdst,
                                                        const int* __restrict__ offs,
                                                        const int* __restrict__ csr,
                                                        const float* __restrict__ bias,
                                                        float* __restrict__ out, int n) {
    int node = blockIdx.x * 4 + (threadIdx.x >> 6);
    int lane = threadIdx.x & 63;
    if (node >= n) return;
    int beg = offs[node], end = offs[node + 1];
    float sd = sdst[node];
    float m = -INFINITY, l = 0.f, acc = 0.f;

    for (int base = beg; base < end; base += 64) {
        int j = base + lane;
        bool valid = (j < end);
        int sj = valid ? csr[j] : 0;
        float logit = -INFINITY;
        if (valid) {
            float xv = ssrc[sj] + sd;
            logit = (xv > 0.f) ? xv : NEG_SLOPE * xv;
        }
        float cm = logit;
#pragma unroll
        for (int o = 32; o > 0; o >>= 1) cm = fmaxf(cm, __shfl_xor(cm, o));
        float nm = fmaxf(m, cm);
        float scale = __expf(m - nm);
        float ex = valid ? __expf(logit - nm) : 0.f;
        float es = ex;
#pragma unroll
        for (int o = 32; o > 0; o >>= 1) es += __shfl_xor(es, o);
        l = l * scale + es;
        m = nm;
        acc *= scale;
        int cnt = min(64, end - base);
        for (int t = 0; t < cnt; t += 8) {
#pragma unroll
            for (int u = 0; u < 8; ++u) {
                float a = __shfl(ex, t + u);        // 0 beyond cnt
                int s = __shfl(sj, t + u);          // 0 beyond cnt (safe)
                if (lane < 32) acc = fmaf(a, h[(size_t)s * 32 + lane], acc);
            }
        }
    }
    if (lane < 32) out[(size_t)node * 32 + lane] = acc / l + bias[lane];
}

// ---------------- Launch ----------------

extern "C" void kernel_launch(void* const* d_in, const int* in_sizes, int n_in,
                              void* d_out, int out_size, void* d_ws, size_t ws_size,
                              hipStream_t stream) {
    const float* x   = (const float*)d_in[0];
    const int*   ei  = (const int*)d_in[1];
    const float* W1  = (const float*)d_in[2];
    const float* as1 = (const float*)d_in[3];
    const float* ad1 = (const float*)d_in[4];
    const float* b1  = (const float*)d_in[5];
    const float* W2  = (const float*)d_in[6];
    const float* as2 = (const float*)d_in[7];
    const float* ad2 = (const float*)d_in[8];
    const float* b2  = (const float*)d_in[9];
    const float* W3  = (const float*)d_in[10];
    const float* as3 = (const float*)d_in[11];
    const float* ad3 = (const float*)d_in[12];
    const float* b3  = (const float*)d_in[13];
    float* out = (float*)d_out;

    const int n = in_sizes[0] / 3;     // 50000
    const int E = in_sizes[1] / 2;     // 400000
    const int Etot = E + n;            // with self-loops

    // workspace layout (fp32 activation ping-pong F1/F2)
    char* ws = (char*)d_ws;
    float* F1 = (float*)ws;  ws += (size_t)n * 256 * sizeof(float);   // 51.2 MB
    float* F2 = (float*)ws;  ws += (size_t)n * 256 * sizeof(float);   // 51.2 MB
    u16* Wt2h = (u16*)ws;    ws += (size_t)256 * 256 * sizeof(u16);
    u16* Wt2l = (u16*)ws;    ws += (size_t)256 * 256 * sizeof(u16);
    u16* Wt3h = (u16*)ws;    ws += (size_t)32 * 256 * sizeof(u16);
    u16* Wt3l = (u16*)ws;    ws += (size_t)32 * 256 * sizeof(u16);
    float* ssrc = (float*)ws;  ws += (size_t)n * 4 * sizeof(float);
    float* sdst = (float*)ws;  ws += (size_t)n * 4 * sizeof(float);
    int* deg    = (int*)ws;    ws += (size_t)n * sizeof(int);
    int* offs   = (int*)ws;    ws += (size_t)(n + 1) * sizeof(int) + 12;
    int* cursor = (int*)ws;    ws += (size_t)n * sizeof(int);
    int* csr    = (int*)ws;    ws += (size_t)Etot * sizeof(int);   // keep csr LAST

    // ---- CSR build (by dst) ----
    hipMemsetAsync(deg, 0, (size_t)n * sizeof(int), stream);
    int eblocks = (Etot + 255) / 256;
    edge_count<<<eblocks, 256, 0, stream>>>(ei, E, n, deg);
    scan_kernel<<<1, 1024, 0, stream>>>(deg, offs, cursor, n);
    edge_fill<<<eblocks, 256, 0, stream>>>(ei, E, n, cursor, csr);

    // ---- Weight prep (hi/lo split + transpose) ----
    transpose_split<<<(256 * 256 + 255) / 256, 256, 0, stream>>>(W2, Wt2h, Wt2l, 256, 256);
    transpose_split<<<(256 * 32 + 255) / 256, 256, 0, stream>>>(W3, Wt3h, Wt3l, 256, 32);

    int nb4 = (n + 3) / 4;
    int nb64 = (n + 63) / 64;

    // ---- Layer 1: 3 -> (4 x 64), concat, relu ----
    linear1<<<n, 256, 0, stream>>>(x, W1, F1, n);
    compute_scores<4, 64><<<n, 256, 0, stream>>>(F1, as1, ad1, ssrc, sdst, n);
    gat_aggregate_m4<<<nb4, 256, 0, stream>>>(F1, ssrc, sdst, offs, csr, b1, F2, n);

    // ---- Layer 2: 256 -> (4 x 64), concat, relu ----
    gemm_mfma_split<256><<<nb64, 256, 0, stream>>>(F2, Wt2h, Wt2l, F1, n);
    compute_scores<4, 64><<<n, 256, 0, stream>>>(F1, as2, ad2, ssrc, sdst, n);
    gat_aggregate_m4<<<nb4, 256, 0, stream>>>(F1, ssrc, sdst, offs, csr, b2, F2, n);

    // ---- Layer 3: 256 -> (1 x 32), mean(=identity), no relu ----
    gemm_mfma_split<32><<<nb64, 256, 0, stream>>>(F2, Wt3h, Wt3l, F1, n);
    compute_scores<1, 32><<<nb4, 256, 0, stream>>>(F1, as3, ad3, ssrc, sdst, n);
    gat_aggregate_h1<<<nb4, 256, 0, stream>>>(F1, ssrc, sdst, offs, csr, b3, out, n);
}

// Round 6
// 523.658 us; speedup vs baseline: 1.3001x; 1.3001x over previous
//
#include <hip/hip_runtime.h>
#include <math.h>

// =====================================================================
// 3-layer GAT (PyG GATConv) on MI355X.
// fp32 data plane + split-precision bf16 MFMA GEMMs (hi/lo, fp32-equiv).
// R6: GEMM stages fragment-packed B in LDS (shared across waves) ->
//     MFMA fed by ds_read_b128 instead of latency-bound L2 loads.
//     Aggregates reverted to R4 (cnt-guarded) inner loops.
// =====================================================================

#define NEG_SLOPE 0.2f

typedef unsigned short u16;
typedef short bf16x8 __attribute__((ext_vector_type(8)));
typedef float floatx4 __attribute__((ext_vector_type(4)));

__device__ __forceinline__ float b2f(u16 u) {
    return __uint_as_float(((unsigned int)u) << 16);
}
__device__ __forceinline__ u16 f2b(float f) {
    unsigned int u = __float_as_uint(f);
    unsigned int r = (u + 0x7fffu + ((u >> 16) & 1u)) >> 16;   // RNE
    return (u16)r;
}

// ---------------- CSR build ----------------

__global__ __launch_bounds__(256) void edge_count(const int* __restrict__ ei, int E, int n,
                                                  int* __restrict__ deg) {
    int e = blockIdx.x * blockDim.x + threadIdx.x;
    int Etot = E + n;
    if (e >= Etot) return;
    int dst = (e < E) ? ei[E + e] : (e - E);   // self-loop for e >= E
    atomicAdd(&deg[dst], 1);
}

__global__ __launch_bounds__(1024) void scan_kernel(const int* __restrict__ deg,
                                                    int* __restrict__ offs,
                                                    int* __restrict__ cursor, int n) {
    __shared__ int sdata[1024];
    __shared__ int s_running;
    if (threadIdx.x == 0) s_running = 0;
    __syncthreads();
    const int CHUNK = 1024 * 8;
    for (int base = 0; base < n; base += CHUNK) {
        int vals[8];
        int sum = 0;
#pragma unroll
        for (int r = 0; r < 8; ++r) {
            int i = base + threadIdx.x * 8 + r;
            vals[r] = (i < n) ? deg[i] : 0;
            sum += vals[r];
        }
        sdata[threadIdx.x] = sum;
        __syncthreads();
        for (int off = 1; off < 1024; off <<= 1) {
            int v = (threadIdx.x >= off) ? sdata[threadIdx.x - off] : 0;
            __syncthreads();
            sdata[threadIdx.x] += v;
            __syncthreads();
        }
        int excl = sdata[threadIdx.x] - sum + s_running;
#pragma unroll
        for (int r = 0; r < 8; ++r) {
            int i = base + threadIdx.x * 8 + r;
            if (i < n) { offs[i] = excl; cursor[i] = excl; }
            excl += vals[r];
        }
        __syncthreads();
        if (threadIdx.x == 0) s_running += sdata[1023];
        __syncthreads();
    }
    if (threadIdx.x == 0) offs[n] = s_running;
}

__global__ __launch_bounds__(256) void edge_fill(const int* __restrict__ ei, int E, int n,
                                                 int* __restrict__ cursor,
                                                 int* __restrict__ csr) {
    int e = blockIdx.x * blockDim.x + threadIdx.x;
    int Etot = E + n;
    if (e >= Etot) return;
    int src, dst;
    if (e < E) { src = ei[e]; dst = ei[E + e]; }
    else       { src = e - E; dst = e - E; }
    int pos = atomicAdd(&cursor[dst], 1);
    csr[pos] = src;
}

// -------- Pack W into MFMA-fragment-major hi/lo bf16 ----------------------
// Unit u = kb*CT*64 + ct*64 + lane holds 8 bf16: W[kb*32+(lane>>4)*8+j][ct*16+(lane&15)].

__global__ __launch_bounds__(256) void pack_frag(const float* __restrict__ W,
                                                 u16* __restrict__ Bhi,
                                                 u16* __restrict__ Blo, int N) {
    int CT = N / 16;
    int idx = blockIdx.x * blockDim.x + threadIdx.x;
    if (idx >= 8 * CT * 64) return;
    int lane = idx & 63;
    int ctkb = idx >> 6;
    int ct = ctkb % CT;
    int kb = ctkb / CT;
    int col = ct * 16 + (lane & 15);
    int k0 = kb * 32 + (lane >> 4) * 8;
#pragma unroll
    for (int j = 0; j < 8; ++j) {
        float w = W[(size_t)(k0 + j) * N + col];
        u16 hi = f2b(w);
        Bhi[(size_t)idx * 8 + j] = hi;
        Blo[(size_t)idx * 8 + j] = f2b(w - b2f(hi));
    }
}

// ---------------- Layer-1 linear (K=3), fp32 out ----------------

__global__ __launch_bounds__(256) void linear1(const float* __restrict__ x,
                                               const float* __restrict__ W,
                                               float* __restrict__ out, int n) {
    int node = blockIdx.x;
    if (node >= n) return;
    int c = threadIdx.x;
    float x0 = x[node * 3 + 0], x1 = x[node * 3 + 1], x2 = x[node * 3 + 2];
    out[(size_t)node * 256 + c] = fmaf(x0, W[c], fmaf(x1, W[256 + c], x2 * W[512 + c]));
}

// ------- Split-precision MFMA GEMM with LDS-staged B ---------------------
// out[n x CT*16] = A[n x 256] * W^T. A fp32, split hi/lo in-register.
// B pre-packed fragment-major; per kb a 32-KB (CT=16) slice is staged in
// LDS once per block and shared by all 4 waves via ds_read_b128.
// D = Ahi*Whi + Alo*Whi + Ahi*Wlo (fp32 acc, rel err ~1e-5).

template <int CT>
__global__ __launch_bounds__(256) void gemm_lds(const float* __restrict__ A,
                                                const u16* __restrict__ Bhi,
                                                const u16* __restrict__ Blo,
                                                float* __restrict__ outf, int n) {
    __shared__ __align__(16) u16 sHi[CT * 64 * 8];
    __shared__ __align__(16) u16 sLo[CT * 64 * 8];
    int t = threadIdx.x;
    int w = t >> 6, l = t & 63;
    int m0 = blockIdx.x * 64 + w * 16;
    int lm = l & 15, q = l >> 4;
    floatx4 acc[CT] = {};
    int arow = min(m0 + lm, n - 1);
    const float* aptr = A + (size_t)arow * 256 + q * 8;

    for (int kb = 0; kb < 8; ++kb) {
        __syncthreads();
        // stage B k-slice (CT*64 16-byte units per buffer), coalesced
        for (int u = t; u < CT * 64; u += 256) {
            *(uint4*)&sHi[u * 8] = *(const uint4*)&Bhi[((size_t)kb * CT * 64 + u) * 8];
            *(uint4*)&sLo[u * 8] = *(const uint4*)&Blo[((size_t)kb * CT * 64 + u) * 8];
        }
        // A fragment (overlaps staging)
        float4 a0 = *(const float4*)(aptr + kb * 32);
        float4 a1 = *(const float4*)(aptr + kb * 32 + 4);
        float av[8] = {a0.x, a0.y, a0.z, a0.w, a1.x, a1.y, a1.z, a1.w};
        bf16x8 ahi, alo;
#pragma unroll
        for (int j = 0; j < 8; ++j) {
            u16 hi = f2b(av[j]);
            ahi[j] = (short)hi;
            alo[j] = (short)f2b(av[j] - b2f(hi));
        }
        __syncthreads();
#pragma unroll
        for (int ct = 0; ct < CT; ++ct) {
            bf16x8 bhi = *(const bf16x8*)&sHi[(ct * 64 + l) * 8];
            bf16x8 blo = *(const bf16x8*)&sLo[(ct * 64 + l) * 8];
            acc[ct] = __builtin_amdgcn_mfma_f32_16x16x32_bf16(ahi, bhi, acc[ct], 0, 0, 0);
            acc[ct] = __builtin_amdgcn_mfma_f32_16x16x32_bf16(alo, bhi, acc[ct], 0, 0, 0);
            acc[ct] = __builtin_amdgcn_mfma_f32_16x16x32_bf16(ahi, blo, acc[ct], 0, 0, 0);
        }
    }
#pragma unroll
    for (int ct = 0; ct < CT; ++ct) {
#pragma unroll
        for (int r = 0; r < 4; ++r) {
            int row = m0 + q * 4 + r;
            if (row < n)
                outf[(size_t)row * (CT * 16) + ct * 16 + lm] = acc[ct][r];
        }
    }
}

// ---------------- Attention scores: s_src/s_dst = sum_c h*a ----------------

template <int HEADS, int C>
__global__ __launch_bounds__(256) void compute_scores(const float* __restrict__ h,
                                                      const float* __restrict__ asrc,
                                                      const float* __restrict__ adst,
                                                      float* __restrict__ ssrc,
                                                      float* __restrict__ sdst, int n) {
    int w = blockIdx.x * (blockDim.x >> 6) + (threadIdx.x >> 6);
    int lane = threadIdx.x & 63;
    if (w >= n * HEADS) return;
    int node = w / HEADS;
    int head = w % HEADS;
    float va = 0.f, vb = 0.f;
    if (lane < C) {
        float v = h[(size_t)node * (HEADS * C) + head * C + lane];
        va = v * asrc[head * C + lane];
        vb = v * adst[head * C + lane];
    }
#pragma unroll
    for (int o = 32; o > 0; o >>= 1) {
        va += __shfl_xor(va, o);
        vb += __shfl_xor(vb, o);
    }
    if (lane == 0) { ssrc[w] = va; sdst[w] = vb; }
}

// ---------------- Merged 4-head aggregation (layers 1 & 2) ----------------
// One wave per dst node. Lane l: float4 acc covering channels l*4..l*4+3
// (head hA = l>>4); softmax state for head hB = l&3, edge slot eL = l>>2.

__global__ __launch_bounds__(256) void gat_aggregate_m4(const float* __restrict__ h,
                                                        const float* __restrict__ ssrc,
                                                        const float* __restrict__ sdst,
                                                        const int* __restrict__ offs,
                                                        const int* __restrict__ csr,
                                                        const float* __restrict__ bias,
                                                        float* __restrict__ out, int n) {
    int node = blockIdx.x * 4 + (threadIdx.x >> 6);
    int lane = threadIdx.x & 63;
    if (node >= n) return;
    const int hB = lane & 3;
    const int eL = lane >> 2;
    const int hA = lane >> 4;
    int beg = offs[node], end = offs[node + 1];
    float sd = sdst[node * 4 + hB];
    float m = -INFINITY, l = 0.f;
    float4 acc = make_float4(0.f, 0.f, 0.f, 0.f);

    for (int base = beg; base < end; base += 16) {
        int j = base + eL;
        bool valid = (j < end);
        int sj = valid ? csr[j] : 0;
        float logit = -INFINITY;
        if (valid) {
            float xv = ssrc[sj * 4 + hB] + sd;
            logit = (xv > 0.f) ? xv : NEG_SLOPE * xv;
        }
        float cm = logit;
        cm = fmaxf(cm, __shfl_xor(cm, 4));
        cm = fmaxf(cm, __shfl_xor(cm, 8));
        cm = fmaxf(cm, __shfl_xor(cm, 16));
        cm = fmaxf(cm, __shfl_xor(cm, 32));
        float nm = fmaxf(m, cm);
        float scale = __expf(m - nm);       // m=-inf -> 0
        float ex = valid ? __expf(logit - nm) : 0.f;
        float es = ex;
        es += __shfl_xor(es, 4);
        es += __shfl_xor(es, 8);
        es += __shfl_xor(es, 16);
        es += __shfl_xor(es, 32);
        l = l * scale + es;
        m = nm;
        float sA = __shfl(scale, hA);
        acc.x *= sA; acc.y *= sA; acc.z *= sA; acc.w *= sA;

        int cnt = min(16, end - base);
        for (int t = 0; t < cnt; t += 4) {
#pragma unroll
            for (int u = 0; u < 4; ++u) {
                int tt = t + u;
                float a = __shfl(ex, tt * 4 + hA);   // 0 for invalid edges
                int s = __shfl(sj, tt * 4);          // 0 for invalid (safe addr)
                const float4 hv = *(const float4*)&h[(size_t)s * 256 + lane * 4];
                acc.x = fmaf(a, hv.x, acc.x);
                acc.y = fmaf(a, hv.y, acc.y);
                acc.z = fmaf(a, hv.z, acc.z);
                acc.w = fmaf(a, hv.w, acc.w);
            }
        }
    }
    float lf = __shfl(l, hA);
    float inv = 1.f / lf;
    const float4 bv = *(const float4*)&bias[lane * 4];
    float4 o;
    o.x = fmaxf(fmaf(acc.x, inv, bv.x), 0.f);   // relu (layers 1 & 2)
    o.y = fmaxf(fmaf(acc.y, inv, bv.y), 0.f);
    o.z = fmaxf(fmaf(acc.z, inv, bv.z), 0.f);
    o.w = fmaxf(fmaf(acc.w, inv, bv.w), 0.f);
    *(float4*)&out[(size_t)node * 256 + lane * 4] = o;
}

// ---------------- Single-head aggregation (layer 3, C=32, no relu) --------

__global__ __launch_bounds__(256) void gat_aggregate_h1(const float* __restrict__ h,
                                                        const float* __restrict__ ssrc,
                                                        const float* __restrict__ sdst,
                                                        const int* __restrict__ offs,
                                                        const int* __restrict__ csr,
                                                        const float* __restrict__ bias,
                                                        float* __restrict__ out, int n) {
    int node = blockIdx.x * 4 + (threadIdx.x >> 6);
    int lane = threadIdx.x & 63;
    if (node >= n) return;
    int beg = offs[node], end = offs[node + 1];
    float sd = sdst[node];
    float m = -INFINITY, l = 0.f, acc = 0.f;

    for (int base = beg; base < end; base += 64) {
        int j = base + lane;
        bool valid = (j < end);
        int sj = valid ? csr[j] : 0;
        float logit = -INFINITY;
        if (valid) {
            float xv = ssrc[sj] + sd;
            logit = (xv > 0.f) ? xv : NEG_SLOPE * xv;
        }
        float cm = logit;
#pragma unroll
        for (int o = 32; o > 0; o >>= 1) cm = fmaxf(cm, __shfl_xor(cm, o));
        float nm = fmaxf(m, cm);
        float scale = __expf(m - nm);
        float ex = valid ? __expf(logit - nm) : 0.f;
        float es = ex;
#pragma unroll
        for (int o = 32; o > 0; o >>= 1) es += __shfl_xor(es, o);
        l = l * scale + es;
        m = nm;
        acc *= scale;
        int cnt = min(64, end - base);
        for (int t = 0; t < cnt; t += 4) {
#pragma unroll
            for (int u = 0; u < 4; ++u) {
                float a = __shfl(ex, t + u);
                int s = __shfl(sj, t + u);
                if (lane < 32) acc = fmaf(a, h[(size_t)s * 32 + lane], acc);
            }
        }
    }
    if (lane < 32) out[(size_t)node * 32 + lane] = acc / l + bias[lane];
}

// ---------------- Launch ----------------

extern "C" void kernel_launch(void* const* d_in, const int* in_sizes, int n_in,
                              void* d_out, int out_size, void* d_ws, size_t ws_size,
                              hipStream_t stream) {
    const float* x   = (const float*)d_in[0];
    const int*   ei  = (const int*)d_in[1];
    const float* W1  = (const float*)d_in[2];
    const float* as1 = (const float*)d_in[3];
    const float* ad1 = (const float*)d_in[4];
    const float* b1  = (const float*)d_in[5];
    const float* W2  = (const float*)d_in[6];
    const float* as2 = (const float*)d_in[7];
    const float* ad2 = (const float*)d_in[8];
    const float* b2  = (const float*)d_in[9];
    const float* W3  = (const float*)d_in[10];
    const float* as3 = (const float*)d_in[11];
    const float* ad3 = (const float*)d_in[12];
    const float* b3  = (const float*)d_in[13];
    float* out = (float*)d_out;

    const int n = in_sizes[0] / 3;     // 50000
    const int E = in_sizes[1] / 2;     // 400000
    const int Etot = E + n;            // with self-loops

    // workspace layout (fp32 activation ping-pong F1/F2)
    char* ws = (char*)d_ws;
    float* F1 = (float*)ws;  ws += (size_t)n * 256 * sizeof(float);   // 51.2 MB
    float* F2 = (float*)ws;  ws += (size_t)n * 256 * sizeof(float);   // 51.2 MB
    u16* B2h = (u16*)ws;     ws += (size_t)8 * 16 * 64 * 8 * sizeof(u16);   // 128 KB
    u16* B2l = (u16*)ws;     ws += (size_t)8 * 16 * 64 * 8 * sizeof(u16);
    u16* B3h = (u16*)ws;     ws += (size_t)8 * 2 * 64 * 8 * sizeof(u16);    // 16 KB
    u16* B3l = (u16*)ws;     ws += (size_t)8 * 2 * 64 * 8 * sizeof(u16);
    float* ssrc = (float*)ws;  ws += (size_t)n * 4 * sizeof(float);
    float* sdst = (float*)ws;  ws += (size_t)n * 4 * sizeof(float);
    int* deg    = (int*)ws;    ws += (size_t)n * sizeof(int);
    int* offs   = (int*)ws;    ws += (size_t)(n + 1) * sizeof(int) + 12;
    int* cursor = (int*)ws;    ws += (size_t)n * sizeof(int);
    int* csr    = (int*)ws;    ws += (size_t)Etot * sizeof(int);   // keep csr LAST

    // ---- CSR build (by dst) ----
    hipMemsetAsync(deg, 0, (size_t)n * sizeof(int), stream);
    int eblocks = (Etot + 255) / 256;
    edge_count<<<eblocks, 256, 0, stream>>>(ei, E, n, deg);
    scan_kernel<<<1, 1024, 0, stream>>>(deg, offs, cursor, n);
    edge_fill<<<eblocks, 256, 0, stream>>>(ei, E, n, cursor, csr);

    // ---- Weight prep (fragment-major hi/lo pack) ----
    pack_frag<<<(8 * 16 * 64 + 255) / 256, 256, 0, stream>>>(W2, B2h, B2l, 256);
    pack_frag<<<(8 * 2 * 64 + 255) / 256, 256, 0, stream>>>(W3, B3h, B3l, 32);

    int nb4 = (n + 3) / 4;
    int nb64 = (n + 63) / 64;

    // ---- Layer 1: 3 -> (4 x 64), concat, relu ----
    linear1<<<n, 256, 0, stream>>>(x, W1, F1, n);
    compute_scores<4, 64><<<n, 256, 0, stream>>>(F1, as1, ad1, ssrc, sdst, n);
    gat_aggregate_m4<<<nb4, 256, 0, stream>>>(F1, ssrc, sdst, offs, csr, b1, F2, n);

    // ---- Layer 2: 256 -> (4 x 64), concat, relu ----
    gemm_lds<16><<<nb64, 256, 0, stream>>>(F2, B2h, B2l, F1, n);
    compute_scores<4, 64><<<n, 256, 0, stream>>>(F1, as2, ad2, ssrc, sdst, n);
    gat_aggregate_m4<<<nb4, 256, 0, stream>>>(F1, ssrc, sdst, offs, csr, b2, F2, n);

    // ---- Layer 3: 256 -> (1 x 32), mean(=identity), no relu ----
    gemm_lds<2><<<nb64, 256, 0, stream>>>(F2, B3h, B3l, F1, n);
    compute_scores<1, 32><<<nb4, 256, 0, stream>>>(F1, as3, ad3, ssrc, sdst, n);
    gat_aggregate_h1<<<nb4, 256, 0, stream>>>(F1, ssrc, sdst, offs, csr, b3, out, n);
}

// Round 7
// 453.274 us; speedup vs baseline: 1.5019x; 1.1553x over previous
//
#include <hip/hip_runtime.h>
#include <math.h>

// =====================================================================
// 3-layer GAT (PyG GATConv) on MI355X.
// fp32 data plane + split-precision bf16 MFMA GEMMs (hi/lo, fp32-equiv)
// with LDS-staged fragment-packed B. CSR-by-dst gather aggregation with
// merged-head online softmax.
// R7: single-block scan (76 us, serialization artifact) replaced by a
//     3-phase multi-block scan (~10 us).
// =====================================================================

#define NEG_SLOPE 0.2f

typedef unsigned short u16;
typedef short bf16x8 __attribute__((ext_vector_type(8)));
typedef float floatx4 __attribute__((ext_vector_type(4)));

__device__ __forceinline__ float b2f(u16 u) {
    return __uint_as_float(((unsigned int)u) << 16);
}
__device__ __forceinline__ u16 f2b(float f) {
    unsigned int u = __float_as_uint(f);
    unsigned int r = (u + 0x7fffu + ((u >> 16) & 1u)) >> 16;   // RNE
    return (u16)r;
}

// ---------------- CSR build ----------------

__global__ __launch_bounds__(256) void edge_count(const int* __restrict__ ei, int E, int n,
                                                  int* __restrict__ deg) {
    int e = blockIdx.x * blockDim.x + threadIdx.x;
    int Etot = E + n;
    if (e >= Etot) return;
    int dst = (e < E) ? ei[E + e] : (e - E);   // self-loop for e >= E
    atomicAdd(&deg[dst], 1);
}

// ---- 3-phase multi-block exclusive scan of deg[0..n) -> offs, cursor ----
// Phase A: per-block (1024 elems) sums.
__global__ __launch_bounds__(256) void scan_partials(const int* __restrict__ deg,
                                                     int* __restrict__ partial, int n) {
    __shared__ int red[256];
    int i0 = blockIdx.x * 1024 + threadIdx.x * 4;
    int s = 0;
#pragma unroll
    for (int r = 0; r < 4; ++r) s += (i0 + r < n) ? deg[i0 + r] : 0;
    red[threadIdx.x] = s;
    __syncthreads();
    for (int off = 128; off > 0; off >>= 1) {
        if (threadIdx.x < off) red[threadIdx.x] += red[threadIdx.x + off];
        __syncthreads();
    }
    if (threadIdx.x == 0) partial[blockIdx.x] = red[0];
}

// Phase B: one small block scans the <=128 partials; writes offs[n]=total.
__global__ __launch_bounds__(128) void scan_mid(int* __restrict__ partial, int nb,
                                                int* __restrict__ offs, int n) {
    __shared__ int s[128];
    int v = (threadIdx.x < nb) ? partial[threadIdx.x] : 0;
    s[threadIdx.x] = v;
    __syncthreads();
    for (int off = 1; off < 128; off <<= 1) {
        int t = (threadIdx.x >= off) ? s[threadIdx.x - off] : 0;
        __syncthreads();
        s[threadIdx.x] += t;
        __syncthreads();
    }
    if (threadIdx.x < nb) partial[threadIdx.x] = s[threadIdx.x] - v;   // exclusive
    if (threadIdx.x == nb - 1) offs[n] = s[threadIdx.x];               // total
}

// Phase C: per-block local scan + block offset -> offs, cursor.
__global__ __launch_bounds__(256) void scan_final(const int* __restrict__ deg,
                                                  const int* __restrict__ partial,
                                                  int* __restrict__ offs,
                                                  int* __restrict__ cursor, int n) {
    __shared__ int s[256];
    int i0 = blockIdx.x * 1024 + threadIdx.x * 4;
    int v[4];
    int sum = 0;
#pragma unroll
    for (int r = 0; r < 4; ++r) {
        v[r] = (i0 + r < n) ? deg[i0 + r] : 0;
        sum += v[r];
    }
    s[threadIdx.x] = sum;
    __syncthreads();
    for (int off = 1; off < 256; off <<= 1) {
        int t = (threadIdx.x >= off) ? s[threadIdx.x - off] : 0;
        __syncthreads();
        s[threadIdx.x] += t;
        __syncthreads();
    }
    int excl = s[threadIdx.x] - sum + partial[blockIdx.x];
#pragma unroll
    for (int r = 0; r < 4; ++r) {
        if (i0 + r < n) { offs[i0 + r] = excl; cursor[i0 + r] = excl; }
        excl += v[r];
    }
}

__global__ __launch_bounds__(256) void edge_fill(const int* __restrict__ ei, int E, int n,
                                                 int* __restrict__ cursor,
                                                 int* __restrict__ csr) {
    int e = blockIdx.x * blockDim.x + threadIdx.x;
    int Etot = E + n;
    if (e >= Etot) return;
    int src, dst;
    if (e < E) { src = ei[e]; dst = ei[E + e]; }
    else       { src = e - E; dst = e - E; }
    int pos = atomicAdd(&cursor[dst], 1);
    csr[pos] = src;
}

// -------- Pack W into MFMA-fragment-major hi/lo bf16 ----------------------
// Unit u = kb*CT*64 + ct*64 + lane holds 8 bf16: W[kb*32+(lane>>4)*8+j][ct*16+(lane&15)].

__global__ __launch_bounds__(256) void pack_frag(const float* __restrict__ W,
                                                 u16* __restrict__ Bhi,
                                                 u16* __restrict__ Blo, int N) {
    int CT = N / 16;
    int idx = blockIdx.x * blockDim.x + threadIdx.x;
    if (idx >= 8 * CT * 64) return;
    int lane = idx & 63;
    int ctkb = idx >> 6;
    int ct = ctkb % CT;
    int kb = ctkb / CT;
    int col = ct * 16 + (lane & 15);
    int k0 = kb * 32 + (lane >> 4) * 8;
#pragma unroll
    for (int j = 0; j < 8; ++j) {
        float w = W[(size_t)(k0 + j) * N + col];
        u16 hi = f2b(w);
        Bhi[(size_t)idx * 8 + j] = hi;
        Blo[(size_t)idx * 8 + j] = f2b(w - b2f(hi));
    }
}

// ---------------- Layer-1 linear (K=3), fp32 out ----------------

__global__ __launch_bounds__(256) void linear1(const float* __restrict__ x,
                                               const float* __restrict__ W,
                                               float* __restrict__ out, int n) {
    int node = blockIdx.x;
    if (node >= n) return;
    int c = threadIdx.x;
    float x0 = x[node * 3 + 0], x1 = x[node * 3 + 1], x2 = x[node * 3 + 2];
    out[(size_t)node * 256 + c] = fmaf(x0, W[c], fmaf(x1, W[256 + c], x2 * W[512 + c]));
}

// ------- Split-precision MFMA GEMM with LDS-staged B ---------------------
// out[n x CT*16] = A[n x 256] * W^T. A fp32, split hi/lo in-register.
// B pre-packed fragment-major; per kb a slice is staged in LDS once per
// block and shared by all 4 waves via ds_read_b128.
// D = Ahi*Whi + Alo*Whi + Ahi*Wlo (fp32 acc, rel err ~1e-5).

template <int CT>
__global__ __launch_bounds__(256) void gemm_lds(const float* __restrict__ A,
                                                const u16* __restrict__ Bhi,
                                                const u16* __restrict__ Blo,
                                                float* __restrict__ outf, int n) {
    __shared__ __align__(16) u16 sHi[CT * 64 * 8];
    __shared__ __align__(16) u16 sLo[CT * 64 * 8];
    int t = threadIdx.x;
    int w = t >> 6, l = t & 63;
    int m0 = blockIdx.x * 64 + w * 16;
    int lm = l & 15, q = l >> 4;
    floatx4 acc[CT] = {};
    int arow = min(m0 + lm, n - 1);
    const float* aptr = A + (size_t)arow * 256 + q * 8;

    for (int kb = 0; kb < 8; ++kb) {
        __syncthreads();
        // stage B k-slice (CT*64 16-byte units per buffer), coalesced
        for (int u = t; u < CT * 64; u += 256) {
            *(uint4*)&sHi[u * 8] = *(const uint4*)&Bhi[((size_t)kb * CT * 64 + u) * 8];
            *(uint4*)&sLo[u * 8] = *(const uint4*)&Blo[((size_t)kb * CT * 64 + u) * 8];
        }
        // A fragment (overlaps staging)
        float4 a0 = *(const float4*)(aptr + kb * 32);
        float4 a1 = *(const float4*)(aptr + kb * 32 + 4);
        float av[8] = {a0.x, a0.y, a0.z, a0.w, a1.x, a1.y, a1.z, a1.w};
        bf16x8 ahi, alo;
#pragma unroll
        for (int j = 0; j < 8; ++j) {
            u16 hi = f2b(av[j]);
            ahi[j] = (short)hi;
            alo[j] = (short)f2b(av[j] - b2f(hi));
        }
        __syncthreads();
#pragma unroll
        for (int ct = 0; ct < CT; ++ct) {
            bf16x8 bhi = *(const bf16x8*)&sHi[(ct * 64 + l) * 8];
            bf16x8 blo = *(const bf16x8*)&sLo[(ct * 64 + l) * 8];
            acc[ct] = __builtin_amdgcn_mfma_f32_16x16x32_bf16(ahi, bhi, acc[ct], 0, 0, 0);
            acc[ct] = __builtin_amdgcn_mfma_f32_16x16x32_bf16(alo, bhi, acc[ct], 0, 0, 0);
            acc[ct] = __builtin_amdgcn_mfma_f32_16x16x32_bf16(ahi, blo, acc[ct], 0, 0, 0);
        }
    }
#pragma unroll
    for (int ct = 0; ct < CT; ++ct) {
#pragma unroll
        for (int r = 0; r < 4; ++r) {
            int row = m0 + q * 4 + r;
            if (row < n)
                outf[(size_t)row * (CT * 16) + ct * 16 + lm] = acc[ct][r];
        }
    }
}

// ---------------- Attention scores: s_src/s_dst = sum_c h*a ----------------

template <int HEADS, int C>
__global__ __launch_bounds__(256) void compute_scores(const float* __restrict__ h,
                                                      const float* __restrict__ asrc,
                                                      const float* __restrict__ adst,
                                                      float* __restrict__ ssrc,
                                                      float* __restrict__ sdst, int n) {
    int w = blockIdx.x * (blockDim.x >> 6) + (threadIdx.x >> 6);
    int lane = threadIdx.x & 63;
    if (w >= n * HEADS) return;
    int node = w / HEADS;
    int head = w % HEADS;
    float va = 0.f, vb = 0.f;
    if (lane < C) {
        float v = h[(size_t)node * (HEADS * C) + head * C + lane];
        va = v * asrc[head * C + lane];
        vb = v * adst[head * C + lane];
    }
#pragma unroll
    for (int o = 32; o > 0; o >>= 1) {
        va += __shfl_xor(va, o);
        vb += __shfl_xor(vb, o);
    }
    if (lane == 0) { ssrc[w] = va; sdst[w] = vb; }
}

// ---------------- Merged 4-head aggregation (layers 1 & 2) ----------------
// One wave per dst node. Lane l: float4 acc covering channels l*4..l*4+3
// (head hA = l>>4); softmax state for head hB = l&3, edge slot eL = l>>2.

__global__ __launch_bounds__(256) void gat_aggregate_m4(const float* __restrict__ h,
                                                        const float* __restrict__ ssrc,
                                                        const float* __restrict__ sdst,
                                                        const int* __restrict__ offs,
                                                        const int* __restrict__ csr,
                                                        const float* __restrict__ bias,
                                                        float* __restrict__ out, int n) {
    int node = blockIdx.x * 4 + (threadIdx.x >> 6);
    int lane = threadIdx.x & 63;
    if (node >= n) return;
    const int hB = lane & 3;
    const int eL = lane >> 2;
    const int hA = lane >> 4;
    int beg = offs[node], end = offs[node + 1];
    float sd = sdst[node * 4 + hB];
    float m = -INFINITY, l = 0.f;
    float4 acc = make_float4(0.f, 0.f, 0.f, 0.f);

    for (int base = beg; base < end; base += 16) {
        int j = base + eL;
        bool valid = (j < end);
        int sj = valid ? csr[j] : 0;
        float logit = -INFINITY;
        if (valid) {
            float xv = ssrc[sj * 4 + hB] + sd;
            logit = (xv > 0.f) ? xv : NEG_SLOPE * xv;
        }
        float cm = logit;
        cm = fmaxf(cm, __shfl_xor(cm, 4));
        cm = fmaxf(cm, __shfl_xor(cm, 8));
        cm = fmaxf(cm, __shfl_xor(cm, 16));
        cm = fmaxf(cm, __shfl_xor(cm, 32));
        float nm = fmaxf(m, cm);
        float scale = __expf(m - nm);       // m=-inf -> 0
        float ex = valid ? __expf(logit - nm) : 0.f;
        float es = ex;
        es += __shfl_xor(es, 4);
        es += __shfl_xor(es, 8);
        es += __shfl_xor(es, 16);
        es += __shfl_xor(es, 32);
        l = l * scale + es;
        m = nm;
        float sA = __shfl(scale, hA);
        acc.x *= sA; acc.y *= sA; acc.z *= sA; acc.w *= sA;

        int cnt = min(16, end - base);
        for (int t = 0; t < cnt; t += 4) {
#pragma unroll
            for (int u = 0; u < 4; ++u) {
                int tt = t + u;
                float a = __shfl(ex, tt * 4 + hA);   // 0 for invalid edges
                int s = __shfl(sj, tt * 4);          // 0 for invalid (safe addr)
                const float4 hv = *(const float4*)&h[(size_t)s * 256 + lane * 4];
                acc.x = fmaf(a, hv.x, acc.x);
                acc.y = fmaf(a, hv.y, acc.y);
                acc.z = fmaf(a, hv.z, acc.z);
                acc.w = fmaf(a, hv.w, acc.w);
            }
        }
    }
    float lf = __shfl(l, hA);
    float inv = 1.f / lf;
    const float4 bv = *(const float4*)&bias[lane * 4];
    float4 o;
    o.x = fmaxf(fmaf(acc.x, inv, bv.x), 0.f);   // relu (layers 1 & 2)
    o.y = fmaxf(fmaf(acc.y, inv, bv.y), 0.f);
    o.z = fmaxf(fmaf(acc.z, inv, bv.z), 0.f);
    o.w = fmaxf(fmaf(acc.w, inv, bv.w), 0.f);
    *(float4*)&out[(size_t)node * 256 + lane * 4] = o;
}

// ---------------- Single-head aggregation (layer 3, C=32, no relu) --------

__global__ __launch_bounds__(256) void gat_aggregate_h1(const float* __restrict__ h,
                                                        const float* __restrict__ ssrc,
                                                        const float* __restrict__ sdst,
                                                        const int* __restrict__ offs,
                                                        const int* __restrict__ csr,
                                                        const float* __restrict__ bias,
                                                        float* __restrict__ out, int n) {
    int node = blockIdx.x * 4 + (threadIdx.x >> 6);
    int lane = threadIdx.x & 63;
    if (node >= n) return;
    int beg = offs[node], end = offs[node + 1];
    float sd = sdst[node];
    float m = -INFINITY, l = 0.f, acc = 0.f;

    for (int base = beg; base < end; base += 64) {
        int j = base + lane;
        bool valid = (j < end);
        int sj = valid ? csr[j] : 0;
        float logit = -INFINITY;
        if (valid) {
            float xv = ssrc[sj] + sd;
            logit = (xv > 0.f) ? xv : NEG_SLOPE * xv;
        }
        float cm = logit;
#pragma unroll
        for (int o = 32; o > 0; o >>= 1) cm = fmaxf(cm, __shfl_xor(cm, o));
        float nm = fmaxf(m, cm);
        float scale = __expf(m - nm);
        float ex = valid ? __expf(logit - nm) : 0.f;
        float es = ex;
#pragma unroll
        for (int o = 32; o > 0; o >>= 1) es += __shfl_xor(es, o);
        l = l * scale + es;
        m = nm;
        acc *= scale;
        int cnt = min(64, end - base);
        for (int t = 0; t < cnt; t += 4) {
#pragma unroll
            for (int u = 0; u < 4; ++u) {
                float a = __shfl(ex, t + u);
                int s = __shfl(sj, t + u);
                if (lane < 32) acc = fmaf(a, h[(size_t)s * 32 + lane], acc);
            }
        }
    }
    if (lane < 32) out[(size_t)node * 32 + lane] = acc / l + bias[lane];
}

// ---------------- Launch ----------------

extern "C" void kernel_launch(void* const* d_in, const int* in_sizes, int n_in,
                              void* d_out, int out_size, void* d_ws, size_t ws_size,
                              hipStream_t stream) {
    const float* x   = (const float*)d_in[0];
    const int*   ei  = (const int*)d_in[1];
    const float* W1  = (const float*)d_in[2];
    const float* as1 = (const float*)d_in[3];
    const float* ad1 = (const float*)d_in[4];
    const float* b1  = (const float*)d_in[5];
    const float* W2  = (const float*)d_in[6];
    const float* as2 = (const float*)d_in[7];
    const float* ad2 = (const float*)d_in[8];
    const float* b2  = (const float*)d_in[9];
    const float* W3  = (const float*)d_in[10];
    const float* as3 = (const float*)d_in[11];
    const float* ad3 = (const float*)d_in[12];
    const float* b3  = (const float*)d_in[13];
    float* out = (float*)d_out;

    const int n = in_sizes[0] / 3;     // 50000
    const int E = in_sizes[1] / 2;     // 400000
    const int Etot = E + n;            // with self-loops

    // workspace layout (fp32 activation ping-pong F1/F2)
    char* ws = (char*)d_ws;
    float* F1 = (float*)ws;  ws += (size_t)n * 256 * sizeof(float);   // 51.2 MB
    float* F2 = (float*)ws;  ws += (size_t)n * 256 * sizeof(float);   // 51.2 MB
    u16* B2h = (u16*)ws;     ws += (size_t)8 * 16 * 64 * 8 * sizeof(u16);   // 128 KB
    u16* B2l = (u16*)ws;     ws += (size_t)8 * 16 * 64 * 8 * sizeof(u16);
    u16* B3h = (u16*)ws;     ws += (size_t)8 * 2 * 64 * 8 * sizeof(u16);    // 16 KB
    u16* B3l = (u16*)ws;     ws += (size_t)8 * 2 * 64 * 8 * sizeof(u16);
    float* ssrc = (float*)ws;  ws += (size_t)n * 4 * sizeof(float);
    float* sdst = (float*)ws;  ws += (size_t)n * 4 * sizeof(float);
    int* deg    = (int*)ws;    ws += (size_t)n * sizeof(int);
    int* offs   = (int*)ws;    ws += (size_t)(n + 1) * sizeof(int) + 12;
    int* cursor = (int*)ws;    ws += (size_t)n * sizeof(int);
    int* partial = (int*)ws;   ws += (size_t)128 * sizeof(int);
    int* csr    = (int*)ws;    ws += (size_t)Etot * sizeof(int);   // keep csr LAST

    // ---- CSR build (by dst) ----
    hipMemsetAsync(deg, 0, (size_t)n * sizeof(int), stream);
    int eblocks = (Etot + 255) / 256;
    edge_count<<<eblocks, 256, 0, stream>>>(ei, E, n, deg);
    int sb = (n + 1023) / 1024;                   // 49 scan blocks
    scan_partials<<<sb, 256, 0, stream>>>(deg, partial, n);
    scan_mid<<<1, 128, 0, stream>>>(partial, sb, offs, n);
    scan_final<<<sb, 256, 0, stream>>>(deg, partial, offs, cursor, n);
    edge_fill<<<eblocks, 256, 0, stream>>>(ei, E, n, cursor, csr);

    // ---- Weight prep (fragment-major hi/lo pack) ----
    pack_frag<<<(8 * 16 * 64 + 255) / 256, 256, 0, stream>>>(W2, B2h, B2l, 256);
    pack_frag<<<(8 * 2 * 64 + 255) / 256, 256, 0, stream>>>(W3, B3h, B3l, 32);

    int nb4 = (n + 3) / 4;
    int nb64 = (n + 63) / 64;

    // ---- Layer 1: 3 -> (4 x 64), concat, relu ----
    linear1<<<n, 256, 0, stream>>>(x, W1, F1, n);
    compute_scores<4, 64><<<n, 256, 0, stream>>>(F1, as1, ad1, ssrc, sdst, n);
    gat_aggregate_m4<<<nb4, 256, 0, stream>>>(F1, ssrc, sdst, offs, csr, b1, F2, n);

    // ---- Layer 2: 256 -> (4 x 64), concat, relu ----
    gemm_lds<16><<<nb64, 256, 0, stream>>>(F2, B2h, B2l, F1, n);
    compute_scores<4, 64><<<n, 256, 0, stream>>>(F1, as2, ad2, ssrc, sdst, n);
    gat_aggregate_m4<<<nb4, 256, 0, stream>>>(F1, ssrc, sdst, offs, csr, b2, F2, n);

    // ---- Layer 3: 256 -> (1 x 32), mean(=identity), no relu ----
    gemm_lds<2><<<nb64, 256, 0, stream>>>(F2, B3h, B3l, F1, n);
    compute_scores<1, 32><<<nb4, 256, 0, stream>>>(F1, as3, ad3, ssrc, sdst, n);
    gat_aggregate_h1<<<nb4, 256, 0, stream>>>(F1, ssrc, sdst, offs, csr, b3, out, n);
}

// Round 8
// 348.875 us; speedup vs baseline: 1.9514x; 1.2992x over previous
//
#include <hip/hip_runtime.h>
#include <math.h>

// =====================================================================
// 3-layer GAT (PyG GATConv) on MI355X.
// R8: bf16 value-shadow data plane. Producers (linear1 / MFMA GEMMs)
// write ONLY a bf16 shadow of h and compute attention scores in-register
// from fp32 values (logits stay fp32-exact -> no softmax amplification).
// Aggregates gather bf16 values (half bytes) with fp32 accumulation.
// Split-precision bf16 MFMA GEMMs (hi/lo) with LDS-staged packed B.
// =====================================================================

#define NEG_SLOPE 0.2f

typedef unsigned short u16;
typedef short bf16x8 __attribute__((ext_vector_type(8)));
typedef float floatx4 __attribute__((ext_vector_type(4)));

__device__ __forceinline__ float b2f(u16 u) {
    return __uint_as_float(((unsigned int)u) << 16);
}
__device__ __forceinline__ u16 f2b(float f) {
    unsigned int u = __float_as_uint(f);
    unsigned int r = (u + 0x7fffu + ((u >> 16) & 1u)) >> 16;   // RNE
    return (u16)r;
}

// ---------------- CSR build ----------------

__global__ __launch_bounds__(256) void edge_count(const int* __restrict__ ei, int E, int n,
                                                  int* __restrict__ deg) {
    int e = blockIdx.x * blockDim.x + threadIdx.x;
    int Etot = E + n;
    if (e >= Etot) return;
    int dst = (e < E) ? ei[E + e] : (e - E);   // self-loop for e >= E
    atomicAdd(&deg[dst], 1);
}

__global__ __launch_bounds__(256) void scan_partials(const int* __restrict__ deg,
                                                     int* __restrict__ partial, int n) {
    __shared__ int red[256];
    int i0 = blockIdx.x * 1024 + threadIdx.x * 4;
    int s = 0;
#pragma unroll
    for (int r = 0; r < 4; ++r) s += (i0 + r < n) ? deg[i0 + r] : 0;
    red[threadIdx.x] = s;
    __syncthreads();
    for (int off = 128; off > 0; off >>= 1) {
        if (threadIdx.x < off) red[threadIdx.x] += red[threadIdx.x + off];
        __syncthreads();
    }
    if (threadIdx.x == 0) partial[blockIdx.x] = red[0];
}

__global__ __launch_bounds__(128) void scan_mid(int* __restrict__ partial, int nb,
                                                int* __restrict__ offs, int n) {
    __shared__ int s[128];
    int v = (threadIdx.x < nb) ? partial[threadIdx.x] : 0;
    s[threadIdx.x] = v;
    __syncthreads();
    for (int off = 1; off < 128; off <<= 1) {
        int t = (threadIdx.x >= off) ? s[threadIdx.x - off] : 0;
        __syncthreads();
        s[threadIdx.x] += t;
        __syncthreads();
    }
    if (threadIdx.x < nb) partial[threadIdx.x] = s[threadIdx.x] - v;   // exclusive
    if (threadIdx.x == nb - 1) offs[n] = s[threadIdx.x];               // total
}

__global__ __launch_bounds__(256) void scan_final(const int* __restrict__ deg,
                                                  const int* __restrict__ partial,
                                                  int* __restrict__ offs,
                                                  int* __restrict__ cursor, int n) {
    __shared__ int s[256];
    int i0 = blockIdx.x * 1024 + threadIdx.x * 4;
    int v[4];
    int sum = 0;
#pragma unroll
    for (int r = 0; r < 4; ++r) {
        v[r] = (i0 + r < n) ? deg[i0 + r] : 0;
        sum += v[r];
    }
    s[threadIdx.x] = sum;
    __syncthreads();
    for (int off = 1; off < 256; off <<= 1) {
        int t = (threadIdx.x >= off) ? s[threadIdx.x - off] : 0;
        __syncthreads();
        s[threadIdx.x] += t;
        __syncthreads();
    }
    int excl = s[threadIdx.x] - sum + partial[blockIdx.x];
#pragma unroll
    for (int r = 0; r < 4; ++r) {
        if (i0 + r < n) { offs[i0 + r] = excl; cursor[i0 + r] = excl; }
        excl += v[r];
    }
}

__global__ __launch_bounds__(256) void edge_fill(const int* __restrict__ ei, int E, int n,
                                                 int* __restrict__ cursor,
                                                 int* __restrict__ csr) {
    int e = blockIdx.x * blockDim.x + threadIdx.x;
    int Etot = E + n;
    if (e >= Etot) return;
    int src, dst;
    if (e < E) { src = ei[e]; dst = ei[E + e]; }
    else       { src = e - E; dst = e - E; }
    int pos = atomicAdd(&cursor[dst], 1);
    csr[pos] = src;
}

// -------- Pack W into MFMA-fragment-major hi/lo bf16 ----------------------

__global__ __launch_bounds__(256) void pack_frag(const float* __restrict__ W,
                                                 u16* __restrict__ Bhi,
                                                 u16* __restrict__ Blo, int N) {
    int CT = N / 16;
    int idx = blockIdx.x * blockDim.x + threadIdx.x;
    if (idx >= 8 * CT * 64) return;
    int lane = idx & 63;
    int ctkb = idx >> 6;
    int ct = ctkb % CT;
    int kb = ctkb / CT;
    int col = ct * 16 + (lane & 15);
    int k0 = kb * 32 + (lane >> 4) * 8;
#pragma unroll
    for (int j = 0; j < 8; ++j) {
        float w = W[(size_t)(k0 + j) * N + col];
        u16 hi = f2b(w);
        Bhi[(size_t)idx * 8 + j] = hi;
        Blo[(size_t)idx * 8 + j] = f2b(w - b2f(hi));
    }
}

// ------- Layer-1 linear (K=3) + fused scores; writes bf16 shadow only -----

__global__ __launch_bounds__(256) void linear1(const float* __restrict__ x,
                                               const float* __restrict__ W,
                                               const float* __restrict__ asrc,
                                               const float* __restrict__ adst,
                                               u16* __restrict__ Hb,
                                               float* __restrict__ ssrc,
                                               float* __restrict__ sdst, int n) {
    int node = blockIdx.x;
    if (node >= n) return;
    int c = threadIdx.x;
    int head = c >> 6, lane = c & 63;
    float x0 = x[node * 3 + 0], x1 = x[node * 3 + 1], x2 = x[node * 3 + 2];
    float v = fmaf(x0, W[c], fmaf(x1, W[256 + c], x2 * W[512 + c]));
    Hb[(size_t)node * 256 + c] = f2b(v);
    float va = v * asrc[c];
    float vb = v * adst[c];
#pragma unroll
    for (int o = 32; o > 0; o >>= 1) {
        va += __shfl_xor(va, o);
        vb += __shfl_xor(vb, o);
    }
    if (lane == 0) { ssrc[node * 4 + head] = va; sdst[node * 4 + head] = vb; }
}

// ------- Split-precision MFMA GEMM, LDS-staged B, fused scores ------------
// out = A[n x 256] * W^T (NCOLS = CT*16). A fp32 split hi/lo in-register;
// D = Ahi*Whi + Alo*Whi + Ahi*Wlo (fp32 acc). Writes bf16 shadow + per-row
// per-head scores computed from fp32 accumulators (logits fp32-exact).
// Fragments: A[m=lane&15][k=(lane>>4)*8+j]; D reg r -> row (l>>4)*4+r, col l&15.

template <int CT, int HEADS>
__global__ __launch_bounds__(256) void gemm_lds(const float* __restrict__ A,
                                                const u16* __restrict__ Bhi,
                                                const u16* __restrict__ Blo,
                                                const float* __restrict__ asrc,
                                                const float* __restrict__ adst,
                                                u16* __restrict__ Hb,
                                                float* __restrict__ ssrc,
                                                float* __restrict__ sdst, int n) {
    __shared__ __align__(16) u16 sHi[CT * 64 * 8];
    __shared__ __align__(16) u16 sLo[CT * 64 * 8];
    int t = threadIdx.x;
    int w = t >> 6, l = t & 63;
    int m0 = blockIdx.x * 64 + w * 16;
    int lm = l & 15, q = l >> 4;
    floatx4 acc[CT] = {};
    int arow = min(m0 + lm, n - 1);
    const float* aptr = A + (size_t)arow * 256 + q * 8;

    for (int kb = 0; kb < 8; ++kb) {
        __syncthreads();
        for (int u = t; u < CT * 64; u += 256) {
            *(uint4*)&sHi[u * 8] = *(const uint4*)&Bhi[((size_t)kb * CT * 64 + u) * 8];
            *(uint4*)&sLo[u * 8] = *(const uint4*)&Blo[((size_t)kb * CT * 64 + u) * 8];
        }
        float4 a0 = *(const float4*)(aptr + kb * 32);
        float4 a1 = *(const float4*)(aptr + kb * 32 + 4);
        float av[8] = {a0.x, a0.y, a0.z, a0.w, a1.x, a1.y, a1.z, a1.w};
        bf16x8 ahi, alo;
#pragma unroll
        for (int j = 0; j < 8; ++j) {
            u16 hi = f2b(av[j]);
            ahi[j] = (short)hi;
            alo[j] = (short)f2b(av[j] - b2f(hi));
        }
        __syncthreads();
#pragma unroll
        for (int ct = 0; ct < CT; ++ct) {
            bf16x8 bhi = *(const bf16x8*)&sHi[(ct * 64 + l) * 8];
            bf16x8 blo = *(const bf16x8*)&sLo[(ct * 64 + l) * 8];
            acc[ct] = __builtin_amdgcn_mfma_f32_16x16x32_bf16(ahi, bhi, acc[ct], 0, 0, 0);
            acc[ct] = __builtin_amdgcn_mfma_f32_16x16x32_bf16(alo, bhi, acc[ct], 0, 0, 0);
            acc[ct] = __builtin_amdgcn_mfma_f32_16x16x32_bf16(ahi, blo, acc[ct], 0, 0, 0);
        }
    }
    // ---- bf16 shadow store ----
#pragma unroll
    for (int ct = 0; ct < CT; ++ct) {
#pragma unroll
        for (int r = 0; r < 4; ++r) {
            int row = m0 + q * 4 + r;
            if (row < n)
                Hb[(size_t)row * (CT * 16) + ct * 16 + lm] = f2b(acc[ct][r]);
        }
    }
    // ---- fused scores: per-row, per-head dot with asrc/adst -------------
    constexpr int CPH = CT / HEADS;          // col-tiles per head
    float ps[4][HEADS] = {}, pd[4][HEADS] = {};
#pragma unroll
    for (int h = 0; h < HEADS; ++h) {
#pragma unroll
        for (int j = 0; j < CPH; ++j) {
            int ct = h * CPH + j;
            float a_s = asrc[ct * 16 + lm];
            float a_d = adst[ct * 16 + lm];
#pragma unroll
            for (int r = 0; r < 4; ++r) {
                ps[r][h] = fmaf(acc[ct][r], a_s, ps[r][h]);
                pd[r][h] = fmaf(acc[ct][r], a_d, pd[r][h]);
            }
        }
    }
#pragma unroll
    for (int r = 0; r < 4; ++r)
#pragma unroll
        for (int h = 0; h < HEADS; ++h)
#pragma unroll
            for (int o = 1; o < 16; o <<= 1) {
                ps[r][h] += __shfl_xor(ps[r][h], o);
                pd[r][h] += __shfl_xor(pd[r][h], o);
            }
#pragma unroll
    for (int h = 0; h < HEADS; ++h) {
        if (lm == h) {
#pragma unroll
            for (int r = 0; r < 4; ++r) {
                int row = m0 + q * 4 + r;
                if (row < n) {
                    ssrc[row * HEADS + h] = ps[r][h];
                    sdst[row * HEADS + h] = pd[r][h];
                }
            }
        }
    }
}

// ---------------- Merged 4-head aggregation (layers 1 & 2) ----------------
// One wave per dst node. Lane l: fp32 float4 acc (channels l*4..+3, head
// hA=l>>4); softmax state head hB=l&3, edge slot eL=l>>2. Values gathered
// bf16 (ushort4), logits fp32-exact from ssrc/sdst tables.

__global__ __launch_bounds__(256) void gat_aggregate_m4(const u16* __restrict__ Hb,
                                                        const float* __restrict__ ssrc,
                                                        const float* __restrict__ sdst,
                                                        const int* __restrict__ offs,
                                                        const int* __restrict__ csr,
                                                        const float* __restrict__ bias,
                                                        float* __restrict__ out, int n) {
    int node = blockIdx.x * 4 + (threadIdx.x >> 6);
    int lane = threadIdx.x & 63;
    if (node >= n) return;
    const int hB = lane & 3;
    const int eL = lane >> 2;
    const int hA = lane >> 4;
    int beg = offs[node], end = offs[node + 1];
    float sd = sdst[node * 4 + hB];
    float m = -INFINITY, l = 0.f;
    float4 acc = make_float4(0.f, 0.f, 0.f, 0.f);

    for (int base = beg; base < end; base += 16) {
        int j = base + eL;
        bool valid = (j < end);
        int sj = valid ? csr[j] : 0;
        float logit = -INFINITY;
        if (valid) {
            float xv = ssrc[sj * 4 + hB] + sd;
            logit = (xv > 0.f) ? xv : NEG_SLOPE * xv;
        }
        float cm = logit;
        cm = fmaxf(cm, __shfl_xor(cm, 4));
        cm = fmaxf(cm, __shfl_xor(cm, 8));
        cm = fmaxf(cm, __shfl_xor(cm, 16));
        cm = fmaxf(cm, __shfl_xor(cm, 32));
        float nm = fmaxf(m, cm);
        float scale = __expf(m - nm);       // m=-inf -> 0
        float ex = valid ? __expf(logit - nm) : 0.f;
        float es = ex;
        es += __shfl_xor(es, 4);
        es += __shfl_xor(es, 8);
        es += __shfl_xor(es, 16);
        es += __shfl_xor(es, 32);
        l = l * scale + es;
        m = nm;
        float sA = __shfl(scale, hA);
        acc.x *= sA; acc.y *= sA; acc.z *= sA; acc.w *= sA;

        int cnt = min(16, end - base);
        for (int t = 0; t < cnt; t += 4) {
#pragma unroll
            for (int u = 0; u < 4; ++u) {
                int tt = t + u;
                float a = __shfl(ex, tt * 4 + hA);   // 0 for invalid edges
                int s = __shfl(sj, tt * 4);          // 0 for invalid (safe addr)
                ushort4 hv = *(const ushort4*)&Hb[(size_t)s * 256 + lane * 4];
                acc.x = fmaf(a, b2f(hv.x), acc.x);
                acc.y = fmaf(a, b2f(hv.y), acc.y);
                acc.z = fmaf(a, b2f(hv.z), acc.z);
                acc.w = fmaf(a, b2f(hv.w), acc.w);
            }
        }
    }
    float lf = __shfl(l, hA);
    float inv = 1.f / lf;
    const float4 bv = *(const float4*)&bias[lane * 4];
    float4 o;
    o.x = fmaxf(fmaf(acc.x, inv, bv.x), 0.f);   // relu (layers 1 & 2)
    o.y = fmaxf(fmaf(acc.y, inv, bv.y), 0.f);
    o.z = fmaxf(fmaf(acc.z, inv, bv.z), 0.f);
    o.w = fmaxf(fmaf(acc.w, inv, bv.w), 0.f);
    *(float4*)&out[(size_t)node * 256 + lane * 4] = o;
}

// ---------------- Single-head aggregation (layer 3, C=32, no relu) --------

__global__ __launch_bounds__(256) void gat_aggregate_h1(const u16* __restrict__ Hb,
                                                        const float* __restrict__ ssrc,
                                                        const float* __restrict__ sdst,
                                                        const int* __restrict__ offs,
                                                        const int* __restrict__ csr,
                                                        const float* __restrict__ bias,
                                                        float* __restrict__ out, int n) {
    int node = blockIdx.x * 4 + (threadIdx.x >> 6);
    int lane = threadIdx.x & 63;
    if (node >= n) return;
    int beg = offs[node], end = offs[node + 1];
    float sd = sdst[node];
    float m = -INFINITY, l = 0.f, acc = 0.f;

    for (int base = beg; base < end; base += 64) {
        int j = base + lane;
        bool valid = (j < end);
        int sj = valid ? csr[j] : 0;
        float logit = -INFINITY;
        if (valid) {
            float xv = ssrc[sj] + sd;
            logit = (xv > 0.f) ? xv : NEG_SLOPE * xv;
        }
        float cm = logit;
#pragma unroll
        for (int o = 32; o > 0; o >>= 1) cm = fmaxf(cm, __shfl_xor(cm, o));
        float nm = fmaxf(m, cm);
        float scale = __expf(m - nm);
        float ex = valid ? __expf(logit - nm) : 0.f;
        float es = ex;
#pragma unroll
        for (int o = 32; o > 0; o >>= 1) es += __shfl_xor(es, o);
        l = l * scale + es;
        m = nm;
        acc *= scale;
        int cnt = min(64, end - base);
        for (int t = 0; t < cnt; t += 4) {
#pragma unroll
            for (int u = 0; u < 4; ++u) {
                float a = __shfl(ex, t + u);
                int s = __shfl(sj, t + u);
                if (lane < 32) acc = fmaf(a, b2f(Hb[(size_t)s * 32 + lane]), acc);
            }
        }
    }
    if (lane < 32) out[(size_t)node * 32 + lane] = acc / l + bias[lane];
}

// ---------------- Launch ----------------

extern "C" void kernel_launch(void* const* d_in, const int* in_sizes, int n_in,
                              void* d_out, int out_size, void* d_ws, size_t ws_size,
                              hipStream_t stream) {
    const float* x   = (const float*)d_in[0];
    const int*   ei  = (const int*)d_in[1];
    const float* W1  = (const float*)d_in[2];
    const float* as1 = (const float*)d_in[3];
    const float* ad1 = (const float*)d_in[4];
    const float* b1  = (const float*)d_in[5];
    const float* W2  = (const float*)d_in[6];
    const float* as2 = (const float*)d_in[7];
    const float* ad2 = (const float*)d_in[8];
    const float* b2  = (const float*)d_in[9];
    const float* W3  = (const float*)d_in[10];
    const float* as3 = (const float*)d_in[11];
    const float* ad3 = (const float*)d_in[12];
    const float* b3  = (const float*)d_in[13];
    float* out = (float*)d_out;

    const int n = in_sizes[0] / 3;     // 50000
    const int E = in_sizes[1] / 2;     // 400000
    const int Etot = E + n;            // with self-loops

    // workspace layout (~84 MB)
    char* ws = (char*)d_ws;
    float* F  = (float*)ws;  ws += (size_t)n * 256 * sizeof(float);   // 51.2 MB fp32 ping
    u16* Hb   = (u16*)ws;    ws += (size_t)n * 256 * sizeof(u16);     // 25.6 MB bf16 shadow
    u16* Hb3  = (u16*)ws;    ws += (size_t)n * 32 * sizeof(u16);      // 3.2 MB
    u16* B2h  = (u16*)ws;    ws += (size_t)8 * 16 * 64 * 8 * sizeof(u16);
    u16* B2l  = (u16*)ws;    ws += (size_t)8 * 16 * 64 * 8 * sizeof(u16);
    u16* B3h  = (u16*)ws;    ws += (size_t)8 * 2 * 64 * 8 * sizeof(u16);
    u16* B3l  = (u16*)ws;    ws += (size_t)8 * 2 * 64 * 8 * sizeof(u16);
    float* ssrc = (float*)ws;  ws += (size_t)n * 4 * sizeof(float);
    float* sdst = (float*)ws;  ws += (size_t)n * 4 * sizeof(float);
    int* deg    = (int*)ws;    ws += (size_t)n * sizeof(int);
    int* offs   = (int*)ws;    ws += (size_t)(n + 1) * sizeof(int) + 12;
    int* cursor = (int*)ws;    ws += (size_t)n * sizeof(int);
    int* partial = (int*)ws;   ws += (size_t)128 * sizeof(int);
    int* csr    = (int*)ws;    ws += (size_t)Etot * sizeof(int);   // keep csr LAST

    // ---- CSR build (by dst) ----
    hipMemsetAsync(deg, 0, (size_t)n * sizeof(int), stream);
    int eblocks = (Etot + 255) / 256;
    edge_count<<<eblocks, 256, 0, stream>>>(ei, E, n, deg);
    int sb = (n + 1023) / 1024;
    scan_partials<<<sb, 256, 0, stream>>>(deg, partial, n);
    scan_mid<<<1, 128, 0, stream>>>(partial, sb, offs, n);
    scan_final<<<sb, 256, 0, stream>>>(deg, partial, offs, cursor, n);
    edge_fill<<<eblocks, 256, 0, stream>>>(ei, E, n, cursor, csr);

    // ---- Weight prep (fragment-major hi/lo pack) ----
    pack_frag<<<(8 * 16 * 64 + 255) / 256, 256, 0, stream>>>(W2, B2h, B2l, 256);
    pack_frag<<<(8 * 2 * 64 + 255) / 256, 256, 0, stream>>>(W3, B3h, B3l, 32);

    int nb4 = (n + 3) / 4;
    int nb64 = (n + 63) / 64;

    // ---- Layer 1: 3 -> (4 x 64), concat, relu ----
    linear1<<<n, 256, 0, stream>>>(x, W1, as1, ad1, Hb, ssrc, sdst, n);
    gat_aggregate_m4<<<nb4, 256, 0, stream>>>(Hb, ssrc, sdst, offs, csr, b1, F, n);

    // ---- Layer 2: 256 -> (4 x 64), concat, relu ----
    gemm_lds<16, 4><<<nb64, 256, 0, stream>>>(F, B2h, B2l, as2, ad2, Hb, ssrc, sdst, n);
    gat_aggregate_m4<<<nb4, 256, 0, stream>>>(Hb, ssrc, sdst, offs, csr, b2, F, n);

    // ---- Layer 3: 256 -> (1 x 32), mean(=identity), no relu ----
    gemm_lds<2, 1><<<nb64, 256, 0, stream>>>(F, B3h, B3l, as3, ad3, Hb3, ssrc, sdst, n);
    gat_aggregate_h1<<<nb4, 256, 0, stream>>>(Hb3, ssrc, sdst, offs, csr, b3, out, n);
}